// Round 6
// baseline (222.204 us; speedup 1.0000x reference)
//
#include <hip/hip_runtime.h>

#define TID ((int)threadIdx.x)
typedef unsigned short u16;
typedef short short8 __attribute__((ext_vector_type(8)));
typedef float f32x4 __attribute__((ext_vector_type(4)));

__device__ __forceinline__ u16 f2b(float f) {
    unsigned int x = __float_as_uint(f);
    return (u16)((x + 0x7fffu + ((x >> 16) & 1u)) >> 16);
}
__device__ __forceinline__ float b2f(u16 u) {
    return __uint_as_float(((unsigned int)u) << 16);
}
// RNE f32x2 -> packed bf16x2 in ONE VALU op (bit-identical to f2b pair).
__device__ __forceinline__ unsigned int cvt_pk(float lo, float hi) {
    unsigned int r;
    asm("v_cvt_pk_bf16_f32 %0, %1, %2" : "=v"(r) : "v"(lo), "v"(hi));
    return r;
}
// max(w[l], w[l^32]) in every lane via VALU permlane (no LDS pipe).
__device__ __forceinline__ float xmax32(float w) {
    unsigned int a = __float_as_uint(w), b = a;
    asm("v_permlane32_swap_b32 %0, %1" : "+v"(a), "+v"(b));
    return fmaxf(__uint_as_float(a), __uint_as_float(b));
}

// ---------------- workspace layout (BYTE offsets) ----------------
static constexpr size_t OFF_QW1   = 0;         // 800 f32 [32][25]
static constexpr size_t OFF_QWF2  = 3200;      // 5120 f32 [10][512]
static constexpr size_t OFF_TMAX  = 23680;     // 4 uint
static constexpr size_t OFF_SUM1C = 23808;     // f32 [8 copies][32]
static constexpr size_t OFF_SSQ1C = 24832;     // f32 [8][32]
static constexpr size_t OFF_SUM2  = 25856, OFF_SSQ2 = 26112;   // f32 [64]
static constexpr size_t OFF_SUM3  = 26368, OFF_SSQ3 = 28416;   // f32 [512]
static constexpr size_t STATS_BEG = 23680, STATS_END = 30464;
static constexpr size_t OFF_QW2C  = 30720;     // bf16 [25 shift][64 oc][32 ic]
static constexpr size_t OFF_QWF1C = 133120;    // bf16 [512][1024]
static constexpr size_t OFF_Y1P   = 1181696;   // bf16 [4096][144][32]  PRE-BN pooled conv1
static constexpr size_t OFF_H2P   = 38930432;  // bf16 [4096][1024]     PRE-BN pooled conv2
static constexpr size_t OFF_Y3    = 47319040;  // f32 [512][4096]
// total ~55.7 MB

// ---------------- abs-max of the 4 weight tensors ----------------
__global__ __launch_bounds__(256) void absmax_k(const float* w1, const float* w2,
                                                const float* wf1, const float* wf2,
                                                unsigned int* tmaxbits) {
    int bid = blockIdx.x;
    int b, lb, nb; const float* src; long n;
    if (bid < 1)        { b = 0; src = w1;  n = 800;    lb = bid;       nb = 1;   }
    else if (bid < 9)   { b = 1; src = w2;  n = 51200;  lb = bid - 1;   nb = 8;   }
    else if (bid < 265) { b = 2; src = wf1; n = 524288; lb = bid - 9;   nb = 256; }
    else                { b = 3; src = wf2; n = 5120;   lb = bid - 265; nb = 1;   }
    float m = 0.f;
    for (long i = (long)lb * 256 + TID; i < n; i += (long)nb * 256)
        m = fmaxf(m, fabsf(src[i]));
    __shared__ float red[256];
    red[TID] = m; __syncthreads();
    for (int s = 128; s > 0; s >>= 1) {
        if (TID < s) red[TID] = fmaxf(red[TID], red[TID + s]);
        __syncthreads();
    }
    if (TID == 0) atomicMax(&tmaxbits[b], __float_as_uint(red[0]));
}

// ---------------- all 4 quantizers in one launch ----------------
// r4: quantized bf16 outputs are exact constants {0,±1} -> literal bit patterns.
__global__ __launch_bounds__(256) void quant_all_k(const float* w1, const float* w2,
                                                   const float* wf1, const float* wf2,
                                                   float* qw1, u16* qw2c, u16* qwf1c,
                                                   float* qwf2, const unsigned int* tmax) {
    int bid = blockIdx.x;
    if (bid < 4) {
        int i = bid * 256 + TID; if (i >= 800) return;
        float t = 0.05f * __uint_as_float(tmax[0]);
        float v = w1[i];
        qw1[i] = (v > t) ? 1.f : ((v < -t) ? -1.f : 0.f);
    } else if (bid < 204) {
        int i = (bid - 4) * 256 + TID;       // < 51200
        float t = 0.05f * __uint_as_float(tmax[1]);
        int ic = i & 31, oc = (i >> 5) & 63, sh = i >> 11;
        float v = w2[(oc * 32 + ic) * 25 + sh];
        qw2c[i] = (v > t) ? (u16)0x3F80 : ((v < -t) ? (u16)0xBF80 : (u16)0);
    } else if (bid < 2252) {
        int i = (bid - 204) * 256 + TID;     // < 524288
        float t = 0.05f * __uint_as_float(tmax[2]);
        float v = wf1[i];
        qwf1c[i] = (v > t) ? (u16)0x3F80 : ((v < -t) ? (u16)0xBF80 : (u16)0);
    } else {
        int i = (bid - 2252) * 256 + TID;    // < 5120
        float t = 0.05f * __uint_as_float(tmax[3]);
        float v = wf2[i];
        qwf2[i] = (v > t) ? 1.f : ((v < -t) ? -1.f : 0.f);
    }
}

// ---------------- conv1 via MFMA, samples-as-M ----------------
// Block = 16 samples x (6 pooled rows [ph]) x (6 pooled cols [pch]); grid 1024.
// r4: staging + output conversions via v_cvt_pk_bf16_f32 (RNE, bit-identical).
__global__ __launch_bounds__(256) void conv1_fused_k(const float* __restrict__ x,
                                                     const float* __restrict__ qw1,
                                                     u16* __restrict__ y1p,
                                                     float* sum1c, float* ssq1c) {
    __shared__ __align__(16) u16 xs[16 * 1096];  // [16 smp][rep0 548 | rep1 548]
    int gid = blockIdx.x;                        // 1024 = 256 sg x 2 ph x 2 pch
    int sg = gid >> 2, ph = (gid >> 1) & 1, pch = gid & 1;
    int l = TID & 63, w = TID >> 6;
    int lm = l & 15, q = l >> 4;

    // ---- zero-fill (2192 uint4) ----
    #pragma unroll
    for (int i = 0; i < 9; i++) {
        int idx = TID + i * 256;
        if (idx < 2192) reinterpret_cast<uint4*>(xs)[idx] = make_uint4(0, 0, 0, 0);
    }

    // ---- B fragments (global reads, no LDS dep) ----
    short8 B1[2], B2[2];
    #pragma unroll
    for (int c = 0; c < 2; c++) {
        union { short8 s; u16 h[8]; } b1, b2;
        int ch = c * 16 + lm;
        #pragma unroll
        for (int j = 0; j < 8; j++) {
            float v1 = 0.f, v2 = 0.f;
            if (j < 5) {
                v1 = qw1[ch * 25 + q * 5 + j];
                v2 = qw1[ch * 25 + 20 + j];
            }
            b1.h[j] = f2b(v1);
            b2.h[j] = (q == 0) ? f2b(v2) : (u16)0;
        }
        B1[c] = b1.s; B2[c] = b2.s;
    }
    __syncthreads();

    // ---- stage x rows 12ph..12ph+15 as bf16, 2 shifted replicas ----
    #pragma unroll
    for (int k = 0; k < 7; k++) {
        int i = TID + k * 256;                   // < 1792 exactly
        int smp = i / 112, rem = i % 112;
        int row = rem / 7, c4 = (rem % 7) * 4;
        float4 v = *reinterpret_cast<const float4*>(
            x + (size_t)(sg * 16 + smp) * 784 + (12 * ph + row) * 28 + c4);
        unsigned int r0 = cvt_pk(v.x, v.y), r1 = cvt_pk(v.z, v.w);
        uint2 pk; pk.x = r0; pk.y = r1;
        *reinterpret_cast<uint2*>(xs + smp * 1096 + row * 32 + c4) = pk;
        u16 h[4] = {(u16)r0, (u16)(r0 >> 16), (u16)r1, (u16)(r1 >> 16)};
        u16* b1p = xs + smp * 1096 + 548 + row * 32;
        #pragma unroll
        for (int e = 0; e < 4; e++) {
            int c = c4 + e;
            if (c >= 1) b1p[c - 1] = h[e];
        }
    }
    __syncthreads();

    // ---- compute: wave w handles 9 pooled positions ----
    float s0 = 0.f, s1 = 0.f, q0 = 0.f, q1 = 0.f;
    int laneoff = lm * 1096;
    #pragma unroll 1
    for (int e = 0; e < 9; e++) {
        int pp = w * 9 + e;                      // 0..35
        int prl = pp / 6, pcl = pp - prl * 6;
        f32x4 pm0 = {-3.0e38f, -3.0e38f, -3.0e38f, -3.0e38f};
        f32x4 pm1 = pm0;
        #pragma unroll
        for (int dyx = 0; dyx < 4; dyx++) {
            int dy = dyx >> 1, dx = dyx & 1;
            int oyl = 2 * prl + dy;              // local conv row 0..11
            int ox = 2 * (pch * 6 + pcl) + dx;   // global conv col 0..23
            int r = ox & 1, cb = ox - r;
            const u16* p1 = xs + laneoff + r * 548 + (oyl + q) * 32 + cb;
            const u16* p2 = xs + laneoff + r * 548 + (oyl + 4) * 32 + cb;
            union { short8 s; unsigned int u[4]; } a1, a2;
            #pragma unroll
            for (int t = 0; t < 4; t++) {
                a1.u[t] = *reinterpret_cast<const unsigned int*>(p1 + 2 * t);
                a2.u[t] = *reinterpret_cast<const unsigned int*>(p2 + 2 * t);
            }
            f32x4 d0 = {0.f, 0.f, 0.f, 0.f};
            d0 = __builtin_amdgcn_mfma_f32_16x16x32_bf16(a1.s, B1[0], d0, 0, 0, 0);
            d0 = __builtin_amdgcn_mfma_f32_16x16x32_bf16(a2.s, B2[0], d0, 0, 0, 0);
            f32x4 d1 = {0.f, 0.f, 0.f, 0.f};
            d1 = __builtin_amdgcn_mfma_f32_16x16x32_bf16(a1.s, B1[1], d1, 0, 0, 0);
            d1 = __builtin_amdgcn_mfma_f32_16x16x32_bf16(a2.s, B2[1], d1, 0, 0, 0);
            #pragma unroll
            for (int i = 0; i < 4; i++) {
                float v = d0[i]; s0 += v; q0 = fmaf(v, v, q0);
                float u = d1[i]; s1 += u; q1 = fmaf(u, u, q1);
            }
            pm0 = __builtin_elementwise_max(pm0, d0);
            pm1 = __builtin_elementwise_max(pm1, d1);
        }
        int ppg = (ph * 6 + prl) * 12 + (pch * 6 + pcl);
        #pragma unroll
        for (int i = 0; i < 4; i++) {
            size_t nb = (size_t)(sg * 16 + 4 * q + i) * 4608 + ppg * 32;
            unsigned int r = cvt_pk(pm0[i], pm1[i]);
            y1p[nb + lm]      = (u16)r;
            y1p[nb + 16 + lm] = (u16)(r >> 16);
        }
    }
    // ---- stats: lanes l, l^16, l^32, l^48 share channel (sum over 16 samples) ----
    s0 += __shfl_xor(s0, 16); s0 += __shfl_xor(s0, 32);
    s1 += __shfl_xor(s1, 16); s1 += __shfl_xor(s1, 32);
    q0 += __shfl_xor(q0, 16); q0 += __shfl_xor(q0, 32);
    q1 += __shfl_xor(q1, 16); q1 += __shfl_xor(q1, 32);
    if (l < 16) {
        int slot = (blockIdx.x & 7) * 32;
        atomicAdd(&sum1c[slot + l], s0);
        atomicAdd(&sum1c[slot + 16 + l], s1);
        atomicAdd(&ssq1c[slot + l], q0);
        atomicAdd(&ssq1c[slot + 16 + l], q1);
    }
}

// ---------------- conv2: MFMA implicit conv; BN1+relu in staging; pre-BN pooled epilogue ----------------
// r1: T14 async-STAGE split (44.9 -> 42.0 measured). r4: cvt_pk/permlane (~ -2).
// r5: conv2 is LATENCY-bound (12k cy/iter vs 1.8k cy LDS floor) at 2 waves/SIMD.
// Occupancy lever WITHOUT r0's per-block-overhead penalty: 512-thread blocks, 8 waves
// = TWO independent 4-wave sample-pipelines (group g = wv>>2 handles samples
// n0+{g,2+g,4+g,6+g}), each with a private LDS double-buffer pair (4 x 9408 B).
// Grid stays 512 -> 16 waves/CU = 4 waves/SIMD (exactly the 104-VGPR cap); weight
// prologue still amortized over 8 samples/block. Barrier invariant per group
// identical to r1 (loop-top barrier separates write-late(t) from read(t+1)).
__global__ __launch_bounds__(512) void conv2_k(const u16* __restrict__ y1p,
                                               const u16* __restrict__ qw2c,
                                               u16* __restrict__ h2pre,
                                               const float* sum1c, const float* ssq1c,
                                               const float* g1, const float* be1,
                                               float* sum, float* ssq) {
    __shared__ float4 hsm4[2352];            // 4 x 9408 B
    __shared__ float scs[32], shs[32];
    char* hsraw = (char*)hsm4;
    int n0 = blockIdx.x * 8;                 // grid.x = 512
    int l = TID & 63, wv = TID >> 6;
    int g = wv >> 2;                         // pipeline group 0/1
    int lt = TID & 255;                      // tid within group
    int oc0 = (wv & 3) * 16;
    int lm = l & 15, lr = (l >> 3) & 1, ox = l & 7, bq = l >> 4;
    char* bufA = hsraw + g * 18816;          // group's buffer pair
    if (TID < 32) {
        float s = 0.f, q = 0.f;
        #pragma unroll
        for (int r = 0; r < 8; r++) { s += sum1c[r * 32 + TID]; q += ssq1c[r * 32 + TID]; }
        float m = s * (1.f / 2359296.f);
        float v = q * (1.f / 2359296.f) - m * m;
        float sc = g1[TID] / sqrtf(v + 1e-5f);
        scs[TID] = sc; shs[TID] = be1[TID] - m * sc;
    }
    __syncthreads();
    float scR[8], shR[8];
    {
        int b = TID & 3;
        #pragma unroll
        for (int j = 0; j < 8; j++) { scR[j] = scs[b * 8 + j]; shR[j] = shs[b * 8 + j]; }
    }
    short8 bw[25];
    #pragma unroll
    for (int sh = 0; sh < 25; sh++)
        bw[sh] = *reinterpret_cast<const short8*>(qw2c + ((size_t)sh * 64 + oc0 + lm) * 32 + bq * 8);
    int xy[5];
    #pragma unroll
    for (int kx = 0; kx < 5; kx++) {
        int xx = ox + kx;
        xy[kx] = lr * 784 + xx * 64 + (((bq + (xx >> 1)) & 3) * 16);
    }
    float sacc = 0.f, s2acc = 0.f;
    // ---- prologue: group g stages sample n0+g into its buffer 0 ----
    {
        const uint4* src = reinterpret_cast<const uint4*>(y1p + (size_t)(n0 + g) * 4608);
        #pragma unroll
        for (int k = 0; k < 3; k++) {
            if (k < 2 || lt < 64) {
                int i = lt + k * 256;
                int pix = i >> 2, b = i & 3;
                int y = pix / 12, xx = pix - y * 12;
                union { uint4 v; u16 u[8]; } in;
                in.v = src[i];
                float f[8];
                #pragma unroll
                for (int j = 0; j < 8; j++)
                    f[j] = fmaxf(fmaf(b2f(in.u[j]), scR[j], shR[j]), 0.f);
                uint4 o = make_uint4(cvt_pk(f[0], f[1]), cvt_pk(f[2], f[3]),
                                     cvt_pk(f[4], f[5]), cvt_pk(f[6], f[7]));
                *reinterpret_cast<uint4*>(bufA + y * 784 + xx * 64 + (((b + (xx >> 1)) & 3) * 16)) = o;
            }
        }
    }
    #pragma unroll 1
    for (int t = 0; t < 4; t++) {
        __syncthreads();
        // ---- T14 issue-early: group's next sample loads into registers (no wait) ----
        uint4 pf0 = {}, pf1 = {}, pf2 = {};
        if (t < 3) {
            const uint4* src = reinterpret_cast<const uint4*>(y1p + (size_t)(n0 + 2 * (t + 1) + g) * 4608);
            pf0 = src[lt];
            pf1 = src[lt + 256];
            if (lt < 64) pf2 = src[lt + 512];
        }
        // ---- compute from group's buf[t&1] (LDS-only deps) ----
        const char* hb = bufA + (t & 1) * 9408;
        f32x4 acc[4] = {{0.f,0.f,0.f,0.f},{0.f,0.f,0.f,0.f},{0.f,0.f,0.f,0.f},{0.f,0.f,0.f,0.f}};
        #pragma unroll
        for (int R = 0; R <= 10; R++) {
            short8 a[5];
            #pragma unroll
            for (int kx = 0; kx < 5; kx++)
                a[kx] = *reinterpret_cast<const short8*>(hb + xy[kx] + R * 784);
            #pragma unroll
            for (int mt = 0; mt < 4; mt++) {
                int ky = R - 2 * mt;
                if (ky < 0 || ky > 4) continue;
                #pragma unroll
                for (int kx = 0; kx < 5; kx++)
                    acc[mt] = __builtin_amdgcn_mfma_f32_16x16x32_bf16(a[kx], bw[ky * 5 + kx], acc[mt], 0, 0, 0);
            }
        }
        int n = n0 + 2 * t + g;
        u16* hp = h2pre + (size_t)n * 1024 + (oc0 + lm) * 16;
        #pragma unroll
        for (int mt = 0; mt < 4; mt++) {
            float v0 = acc[mt][0], v1 = acc[mt][1], v2 = acc[mt][2], v3 = acc[mt][3];
            sacc += v0 + v1 + v2 + v3;
            s2acc += v0 * v0 + v1 * v1 + v2 * v2 + v3 * v3;
            float w0 = fmaxf(v0, v1), w1 = fmaxf(v2, v3);
            float p0 = xmax32(w0);
            float p1 = xmax32(w1);
            if (bq < 2) {
                *reinterpret_cast<unsigned int*>(hp + mt * 4 + bq * 2) = cvt_pk(p0, p1);
            }
        }
        // ---- T14 write-late: vmcnt-wait here, AFTER ~100 MFMAs hid the latency ----
        if (t < 3) {
            char* dst = bufA + ((t + 1) & 1) * 9408;
            #pragma unroll
            for (int k = 0; k < 3; k++) {
                if (k < 2 || lt < 64) {
                    int i = lt + k * 256;
                    int pix = i >> 2, b = i & 3;
                    int y = pix / 12, xx = pix - y * 12;
                    union { uint4 v; u16 u[8]; } in;
                    in.v = (k == 0) ? pf0 : ((k == 1) ? pf1 : pf2);
                    float f[8];
                    #pragma unroll
                    for (int j = 0; j < 8; j++)
                        f[j] = fmaxf(fmaf(b2f(in.u[j]), scR[j], shR[j]), 0.f);
                    uint4 o = make_uint4(cvt_pk(f[0], f[1]), cvt_pk(f[2], f[3]),
                                         cvt_pk(f[4], f[5]), cvt_pk(f[6], f[7]));
                    *reinterpret_cast<uint4*>(dst + y * 784 + xx * 64 + (((b + (xx >> 1)) & 3) * 16)) = o;
                }
            }
        }
    }
    sacc  += __shfl_xor(sacc, 16);  sacc  += __shfl_xor(sacc, 32);
    s2acc += __shfl_xor(s2acc, 16); s2acc += __shfl_xor(s2acc, 32);
    if (l < 16) { atomicAdd(&sum[oc0 + l], sacc); atomicAdd(&ssq[oc0 + l], s2acc); }
}

// ---------------- fc1: 64x64-tile MFMA GEMM; BN2+relu fused into A-staging ----------------
// r4: A-staging conversion via cvt_pk (4 ops instead of ~32 per 8 elements).
__global__ __launch_bounds__(256) void fc1_k(const u16* __restrict__ h2pre,
                                             const u16* __restrict__ qwf1c,
                                             const float* sum2, const float* ssq2,
                                             const float* g2, const float* be2,
                                             float* __restrict__ y3T,
                                             float* sum3, float* ssq3) {
    __shared__ float4 Asm[576], Bsm[576];
    __shared__ float sc2s[64], sh2s[64];
    u16* AsU = (u16*)Asm; u16* BsU = (u16*)Bsm;
    int m0 = blockIdx.x * 64, j0 = blockIdx.y * 64;
    int l = TID & 63, wv = TID >> 6;
    int lm = l & 15, q = l >> 4;
    int r0 = TID >> 3, c0 = TID & 7;
    if (TID < 64) {
        float m = sum2[TID] * (1.f / 262144.f);
        float v = ssq2[TID] * (1.f / 262144.f) - m * m;
        float s = g2[TID] / sqrtf(v + 1e-5f);
        sc2s[TID] = s; sh2s[TID] = be2[TID] - m * s;
    }
    __syncthreads();
    f32x4 acc[4] = {{0.f,0.f,0.f,0.f},{0.f,0.f,0.f,0.f},{0.f,0.f,0.f,0.f},{0.f,0.f,0.f,0.f}};
    #pragma unroll 1
    for (int kc = 0; kc < 16; kc++) {
        int kk = kc * 64;
        if (kc) __syncthreads();
        int oc = (kk + c0 * 8) >> 4;
        float sc = sc2s[oc], sh = sh2s[oc];
        #pragma unroll
        for (int i = 0; i < 2; i++) {
            int r = i * 32 + r0;
            union { float4 v; u16 h[8]; } in;
            in.v = *reinterpret_cast<const float4*>(h2pre + (size_t)(m0 + r) * 1024 + kk + c0 * 8);
            float f[8];
            #pragma unroll
            for (int e = 0; e < 8; e++)
                f[e] = fmaxf(fmaf(b2f(in.h[e]), sc, sh), 0.f);
            uint4 o = make_uint4(cvt_pk(f[0], f[1]), cvt_pk(f[2], f[3]),
                                 cvt_pk(f[4], f[5]), cvt_pk(f[6], f[7]));
            *reinterpret_cast<uint4*>(AsU + r * 72 + c0 * 8) = o;
            *reinterpret_cast<float4*>(BsU + r * 72 + c0 * 8) =
                *reinterpret_cast<const float4*>(qwf1c + (size_t)(j0 + r) * 1024 + kk + c0 * 8);
        }
        __syncthreads();
        #pragma unroll
        for (int half = 0; half < 2; half++) {
            short8 b = *reinterpret_cast<const short8*>(BsU + (wv * 16 + lm) * 72 + half * 32 + q * 8);
            #pragma unroll
            for (int mt = 0; mt < 4; mt++) {
                short8 a = *reinterpret_cast<const short8*>(AsU + (mt * 16 + lm) * 72 + half * 32 + q * 8);
                acc[mt] = __builtin_amdgcn_mfma_f32_16x16x32_bf16(a, b, acc[mt], 0, 0, 0);
            }
        }
    }
    float s = 0.f, s2 = 0.f;
    #pragma unroll
    for (int mt = 0; mt < 4; mt++) {
        *reinterpret_cast<f32x4*>(y3T + (size_t)(j0 + wv * 16 + lm) * 4096 + m0 + mt * 16 + q * 4) = acc[mt];
        #pragma unroll
        for (int i = 0; i < 4; i++) { float v = acc[mt][i]; s += v; s2 = fmaf(v, v, s2); }
    }
    s  += __shfl_xor(s, 16);  s  += __shfl_xor(s, 32);
    s2 += __shfl_xor(s2, 16); s2 += __shfl_xor(s2, 32);
    if (l < 16) {
        atomicAdd(&sum3[j0 + wv * 16 + l], s);
        atomicAdd(&ssq3[j0 + wv * 16 + l], s2);
    }
}

// ---------------- fc2: BN3 inline + relu + GEMV; grid 256 = 16 n x 16 kslices ----------------
__global__ __launch_bounds__(256) void fc2_k(const float* __restrict__ y3T,
                                             const float* sum3, const float* ssq3,
                                             const float* g3, const float* be3,
                                             const float* __restrict__ qwf2,
                                             const float* bf2, float* __restrict__ out) {
    __shared__ float wlds[5120];
    __shared__ float part[15][160];
    __shared__ float sc3s[512], sh3s[512];
    for (int i = TID; i < 5120; i += 256) wlds[i] = qwf2[i];
    for (int k = TID; k < 512; k += 256) {
        float m = sum3[k] * (1.f / 4096.f);
        float v = ssq3[k] * (1.f / 4096.f) - m * m;
        float s = g3[k] / sqrtf(v + 1e-5f);
        sc3s[k] = s; sh3s[k] = be3[k] - m * s;
    }
    __syncthreads();
    int nl = TID & 15, ks = TID >> 4;
    int n = blockIdx.x * 16 + nl;            // grid.x = 256
    float acc[10] = {};
    for (int k = ks * 32; k < ks * 32 + 32; k++) {
        float v = fmaxf(y3T[(size_t)k * 4096 + n] * sc3s[k] + sh3s[k], 0.f);
        #pragma unroll
        for (int o = 0; o < 10; o++) acc[o] = fmaf(v, wlds[o * 512 + k], acc[o]);
    }
    if (ks > 0) {
        #pragma unroll
        for (int o = 0; o < 10; o++) part[ks - 1][o * 16 + nl] = acc[o];
    }
    __syncthreads();
    if (ks == 0) {
        #pragma unroll
        for (int o = 0; o < 10; o++) {
            float r = acc[o] + bf2[o];
            #pragma unroll
            for (int j = 0; j < 15; j++) r += part[j][o * 16 + nl];
            out[n * 10 + o] = r;
        }
    }
}

extern "C" void kernel_launch(void* const* d_in, const int* in_sizes, int n_in,
                              void* d_out, int out_size, void* d_ws, size_t ws_size,
                              hipStream_t stream) {
    char* wsb = (char*)d_ws;
    const float* x   = (const float*)d_in[0];
    const float* w1  = (const float*)d_in[1];
    // b1/b2/bf1 cancel under training-mode BN
    const float* g1  = (const float*)d_in[3];
    const float* be1 = (const float*)d_in[4];
    const float* w2  = (const float*)d_in[5];
    const float* g2  = (const float*)d_in[7];
    const float* be2 = (const float*)d_in[8];
    const float* wf1 = (const float*)d_in[9];
    const float* g3  = (const float*)d_in[11];
    const float* be3 = (const float*)d_in[12];
    const float* wf2 = (const float*)d_in[13];
    const float* bf2 = (const float*)d_in[14];
    float* out = (float*)d_out;

    unsigned int* tmax = (unsigned int*)(wsb + OFF_TMAX);
    float* qw1   = (float*)(wsb + OFF_QW1);
    float* qwf2  = (float*)(wsb + OFF_QWF2);
    u16*   qw2c  = (u16*)(wsb + OFF_QW2C);
    u16*   qwf1c = (u16*)(wsb + OFF_QWF1C);
    u16*   y1p   = (u16*)(wsb + OFF_Y1P);
    u16*   h2pre = (u16*)(wsb + OFF_H2P);
    float* y3    = (float*)(wsb + OFF_Y3);

    float* sum1c = (float*)(wsb + OFF_SUM1C); float* ssq1c = (float*)(wsb + OFF_SSQ1C);
    float* sum2  = (float*)(wsb + OFF_SUM2);  float* ssq2  = (float*)(wsb + OFF_SSQ2);
    float* sum3  = (float*)(wsb + OFF_SUM3);  float* ssq3  = (float*)(wsb + OFF_SSQ3);

    hipMemsetAsync(wsb + STATS_BEG, 0, STATS_END - STATS_BEG, stream);

    absmax_k<<<266, 256, 0, stream>>>(w1, w2, wf1, wf2, tmax);
    quant_all_k<<<2272, 256, 0, stream>>>(w1, w2, wf1, wf2, qw1, qw2c, qwf1c, qwf2, tmax);

    conv1_fused_k<<<1024, 256, 0, stream>>>(x, qw1, y1p, sum1c, ssq1c);
    conv2_k<<<512, 512, 0, stream>>>(y1p, qw2c, h2pre, sum1c, ssq1c, g1, be1, sum2, ssq2);
    fc1_k<<<dim3(64, 8), 256, 0, stream>>>(h2pre, qwf1c, sum2, ssq2, g2, be2, y3, sum3, ssq3);
    fc2_k<<<256, 256, 0, stream>>>(y3, sum3, ssq3, g3, be3, qwf2, bf2, out);
}

// Round 7
// 194.866 us; speedup vs baseline: 1.1403x; 1.1403x over previous
//
#include <hip/hip_runtime.h>

#define TID ((int)threadIdx.x)
typedef unsigned short u16;
typedef short short8 __attribute__((ext_vector_type(8)));
typedef float f32x4 __attribute__((ext_vector_type(4)));

__device__ __forceinline__ u16 f2b(float f) {
    unsigned int x = __float_as_uint(f);
    return (u16)((x + 0x7fffu + ((x >> 16) & 1u)) >> 16);
}
__device__ __forceinline__ float b2f(u16 u) {
    return __uint_as_float(((unsigned int)u) << 16);
}
// RNE f32x2 -> packed bf16x2 in ONE VALU op (bit-identical to f2b pair).
__device__ __forceinline__ unsigned int cvt_pk(float lo, float hi) {
    unsigned int r;
    asm("v_cvt_pk_bf16_f32 %0, %1, %2" : "=v"(r) : "v"(lo), "v"(hi));
    return r;
}
// max(w[l], w[l^32]) in every lane via VALU permlane (no LDS pipe).
__device__ __forceinline__ float xmax32(float w) {
    unsigned int a = __float_as_uint(w), b = a;
    asm("v_permlane32_swap_b32 %0, %1" : "+v"(a), "+v"(b));
    return fmaxf(__uint_as_float(a), __uint_as_float(b));
}

// ---------------- workspace layout (BYTE offsets) ----------------
static constexpr size_t OFF_QW1   = 0;         // 800 f32 [32][25]
static constexpr size_t OFF_QWF2  = 3200;      // 5120 f32 [10][512]
static constexpr size_t OFF_TMAX  = 23680;     // 4 uint
static constexpr size_t OFF_SUM1C = 23808;     // f32 [8 copies][32]
static constexpr size_t OFF_SSQ1C = 24832;     // f32 [8][32]
static constexpr size_t OFF_SUM2  = 25856, OFF_SSQ2 = 26112;   // f32 [64]
static constexpr size_t OFF_SUM3  = 26368, OFF_SSQ3 = 28416;   // f32 [512]
static constexpr size_t STATS_BEG = 23680, STATS_END = 30464;
static constexpr size_t OFF_QW2C  = 30720;     // bf16 [25 shift][64 oc][32 ic]
static constexpr size_t OFF_QWF1C = 133120;    // bf16 [512][1024]
static constexpr size_t OFF_Y1P   = 1181696;   // bf16 [4096][144][32]  PRE-BN pooled conv1
static constexpr size_t OFF_H2P   = 38930432;  // bf16 [4096][1024]     PRE-BN pooled conv2
static constexpr size_t OFF_Y3    = 47319040;  // f32 [512][4096]
// total ~55.7 MB

// ---------------- abs-max of the 4 weight tensors ----------------
__global__ __launch_bounds__(256) void absmax_k(const float* w1, const float* w2,
                                                const float* wf1, const float* wf2,
                                                unsigned int* tmaxbits) {
    int bid = blockIdx.x;
    int b, lb, nb; const float* src; long n;
    if (bid < 1)        { b = 0; src = w1;  n = 800;    lb = bid;       nb = 1;   }
    else if (bid < 9)   { b = 1; src = w2;  n = 51200;  lb = bid - 1;   nb = 8;   }
    else if (bid < 265) { b = 2; src = wf1; n = 524288; lb = bid - 9;   nb = 256; }
    else                { b = 3; src = wf2; n = 5120;   lb = bid - 265; nb = 1;   }
    float m = 0.f;
    for (long i = (long)lb * 256 + TID; i < n; i += (long)nb * 256)
        m = fmaxf(m, fabsf(src[i]));
    __shared__ float red[256];
    red[TID] = m; __syncthreads();
    for (int s = 128; s > 0; s >>= 1) {
        if (TID < s) red[TID] = fmaxf(red[TID], red[TID + s]);
        __syncthreads();
    }
    if (TID == 0) atomicMax(&tmaxbits[b], __float_as_uint(red[0]));
}

// ---------------- all 4 quantizers in one launch ----------------
// r4: quantized bf16 outputs are exact constants {0,±1} -> literal bit patterns.
__global__ __launch_bounds__(256) void quant_all_k(const float* w1, const float* w2,
                                                   const float* wf1, const float* wf2,
                                                   float* qw1, u16* qw2c, u16* qwf1c,
                                                   float* qwf2, const unsigned int* tmax) {
    int bid = blockIdx.x;
    if (bid < 4) {
        int i = bid * 256 + TID; if (i >= 800) return;
        float t = 0.05f * __uint_as_float(tmax[0]);
        float v = w1[i];
        qw1[i] = (v > t) ? 1.f : ((v < -t) ? -1.f : 0.f);
    } else if (bid < 204) {
        int i = (bid - 4) * 256 + TID;       // < 51200
        float t = 0.05f * __uint_as_float(tmax[1]);
        int ic = i & 31, oc = (i >> 5) & 63, sh = i >> 11;
        float v = w2[(oc * 32 + ic) * 25 + sh];
        qw2c[i] = (v > t) ? (u16)0x3F80 : ((v < -t) ? (u16)0xBF80 : (u16)0);
    } else if (bid < 2252) {
        int i = (bid - 204) * 256 + TID;     // < 524288
        float t = 0.05f * __uint_as_float(tmax[2]);
        float v = wf1[i];
        qwf1c[i] = (v > t) ? (u16)0x3F80 : ((v < -t) ? (u16)0xBF80 : (u16)0);
    } else {
        int i = (bid - 2252) * 256 + TID;    // < 5120
        float t = 0.05f * __uint_as_float(tmax[3]);
        float v = wf2[i];
        qwf2[i] = (v > t) ? 1.f : ((v < -t) ? -1.f : 0.f);
    }
}

// ---------------- conv1 via MFMA, samples-as-M ----------------
// Block = 16 samples x (6 pooled rows [ph]) x (6 pooled cols [pch]); grid 1024.
// r4: staging + output conversions via v_cvt_pk_bf16_f32 (RNE, bit-identical).
__global__ __launch_bounds__(256) void conv1_fused_k(const float* __restrict__ x,
                                                     const float* __restrict__ qw1,
                                                     u16* __restrict__ y1p,
                                                     float* sum1c, float* ssq1c) {
    __shared__ __align__(16) u16 xs[16 * 1096];  // [16 smp][rep0 548 | rep1 548]
    int gid = blockIdx.x;                        // 1024 = 256 sg x 2 ph x 2 pch
    int sg = gid >> 2, ph = (gid >> 1) & 1, pch = gid & 1;
    int l = TID & 63, w = TID >> 6;
    int lm = l & 15, q = l >> 4;

    // ---- zero-fill (2192 uint4) ----
    #pragma unroll
    for (int i = 0; i < 9; i++) {
        int idx = TID + i * 256;
        if (idx < 2192) reinterpret_cast<uint4*>(xs)[idx] = make_uint4(0, 0, 0, 0);
    }

    // ---- B fragments (global reads, no LDS dep) ----
    short8 B1[2], B2[2];
    #pragma unroll
    for (int c = 0; c < 2; c++) {
        union { short8 s; u16 h[8]; } b1, b2;
        int ch = c * 16 + lm;
        #pragma unroll
        for (int j = 0; j < 8; j++) {
            float v1 = 0.f, v2 = 0.f;
            if (j < 5) {
                v1 = qw1[ch * 25 + q * 5 + j];
                v2 = qw1[ch * 25 + 20 + j];
            }
            b1.h[j] = f2b(v1);
            b2.h[j] = (q == 0) ? f2b(v2) : (u16)0;
        }
        B1[c] = b1.s; B2[c] = b2.s;
    }
    __syncthreads();

    // ---- stage x rows 12ph..12ph+15 as bf16, 2 shifted replicas ----
    #pragma unroll
    for (int k = 0; k < 7; k++) {
        int i = TID + k * 256;                   // < 1792 exactly
        int smp = i / 112, rem = i % 112;
        int row = rem / 7, c4 = (rem % 7) * 4;
        float4 v = *reinterpret_cast<const float4*>(
            x + (size_t)(sg * 16 + smp) * 784 + (12 * ph + row) * 28 + c4);
        unsigned int r0 = cvt_pk(v.x, v.y), r1 = cvt_pk(v.z, v.w);
        uint2 pk; pk.x = r0; pk.y = r1;
        *reinterpret_cast<uint2*>(xs + smp * 1096 + row * 32 + c4) = pk;
        u16 h[4] = {(u16)r0, (u16)(r0 >> 16), (u16)r1, (u16)(r1 >> 16)};
        u16* b1p = xs + smp * 1096 + 548 + row * 32;
        #pragma unroll
        for (int e = 0; e < 4; e++) {
            int c = c4 + e;
            if (c >= 1) b1p[c - 1] = h[e];
        }
    }
    __syncthreads();

    // ---- compute: wave w handles 9 pooled positions ----
    float s0 = 0.f, s1 = 0.f, q0 = 0.f, q1 = 0.f;
    int laneoff = lm * 1096;
    #pragma unroll 1
    for (int e = 0; e < 9; e++) {
        int pp = w * 9 + e;                      // 0..35
        int prl = pp / 6, pcl = pp - prl * 6;
        f32x4 pm0 = {-3.0e38f, -3.0e38f, -3.0e38f, -3.0e38f};
        f32x4 pm1 = pm0;
        #pragma unroll
        for (int dyx = 0; dyx < 4; dyx++) {
            int dy = dyx >> 1, dx = dyx & 1;
            int oyl = 2 * prl + dy;              // local conv row 0..11
            int ox = 2 * (pch * 6 + pcl) + dx;   // global conv col 0..23
            int r = ox & 1, cb = ox - r;
            const u16* p1 = xs + laneoff + r * 548 + (oyl + q) * 32 + cb;
            const u16* p2 = xs + laneoff + r * 548 + (oyl + 4) * 32 + cb;
            union { short8 s; unsigned int u[4]; } a1, a2;
            #pragma unroll
            for (int t = 0; t < 4; t++) {
                a1.u[t] = *reinterpret_cast<const unsigned int*>(p1 + 2 * t);
                a2.u[t] = *reinterpret_cast<const unsigned int*>(p2 + 2 * t);
            }
            f32x4 d0 = {0.f, 0.f, 0.f, 0.f};
            d0 = __builtin_amdgcn_mfma_f32_16x16x32_bf16(a1.s, B1[0], d0, 0, 0, 0);
            d0 = __builtin_amdgcn_mfma_f32_16x16x32_bf16(a2.s, B2[0], d0, 0, 0, 0);
            f32x4 d1 = {0.f, 0.f, 0.f, 0.f};
            d1 = __builtin_amdgcn_mfma_f32_16x16x32_bf16(a1.s, B1[1], d1, 0, 0, 0);
            d1 = __builtin_amdgcn_mfma_f32_16x16x32_bf16(a2.s, B2[1], d1, 0, 0, 0);
            #pragma unroll
            for (int i = 0; i < 4; i++) {
                float v = d0[i]; s0 += v; q0 = fmaf(v, v, q0);
                float u = d1[i]; s1 += u; q1 = fmaf(u, u, q1);
            }
            pm0 = __builtin_elementwise_max(pm0, d0);
            pm1 = __builtin_elementwise_max(pm1, d1);
        }
        int ppg = (ph * 6 + prl) * 12 + (pch * 6 + pcl);
        #pragma unroll
        for (int i = 0; i < 4; i++) {
            size_t nb = (size_t)(sg * 16 + 4 * q + i) * 4608 + ppg * 32;
            unsigned int r = cvt_pk(pm0[i], pm1[i]);
            y1p[nb + lm]      = (u16)r;
            y1p[nb + 16 + lm] = (u16)(r >> 16);
        }
    }
    // ---- stats: lanes l, l^16, l^32, l^48 share channel (sum over 16 samples) ----
    s0 += __shfl_xor(s0, 16); s0 += __shfl_xor(s0, 32);
    s1 += __shfl_xor(s1, 16); s1 += __shfl_xor(s1, 32);
    q0 += __shfl_xor(q0, 16); q0 += __shfl_xor(q0, 32);
    q1 += __shfl_xor(q1, 16); q1 += __shfl_xor(q1, 32);
    if (l < 16) {
        int slot = (blockIdx.x & 7) * 32;
        atomicAdd(&sum1c[slot + l], s0);
        atomicAdd(&sum1c[slot + 16 + l], s1);
        atomicAdd(&ssq1c[slot + l], q0);
        atomicAdd(&ssq1c[slot + 16 + l], q1);
    }
}

// ---------------- conv2: MFMA implicit conv; BN1+relu in staging; pre-BN pooled epilogue ----------------
// r1: T14 async-STAGE split (44.9 -> 42.0 measured). r4: cvt_pk/permlane (42 -> ~40).
// r6: REVERTED r5's 8-wave dual-pipeline (52us: shared barriers lock-step the two
// groups + 2x per-wave bw[25] prologue; occupancy unchanged). Structural finding:
// per-CU iteration window ~6000cy vs 440 ds_read_b128 x 12cy = 5280cy -> conv2 is at
// ~88% of the LDS-read-issue ceiling for this MFMA decomposition (4 waves read
// identical A addresses; de-duplicating needs ~200 B-VGPRs -> occupancy cliff).
// ~40us is this structure's ceiling. Do not chase occupancy here again.
__global__ __launch_bounds__(256) void conv2_k(const u16* __restrict__ y1p,
                                               const u16* __restrict__ qw2c,
                                               u16* __restrict__ h2pre,
                                               const float* sum1c, const float* ssq1c,
                                               const float* g1, const float* be1,
                                               float* sum, float* ssq) {
    __shared__ float4 hsm4[1176];            // 2 x 9408 B
    __shared__ float scs[32], shs[32];
    char* hsraw = (char*)hsm4;
    int n0 = blockIdx.x * 8;                 // grid.x = 512
    int l = TID & 63, wv = TID >> 6;
    int oc0 = wv * 16;
    int lm = l & 15, lr = (l >> 3) & 1, ox = l & 7, bq = l >> 4;
    if (TID < 32) {
        float s = 0.f, q = 0.f;
        #pragma unroll
        for (int r = 0; r < 8; r++) { s += sum1c[r * 32 + TID]; q += ssq1c[r * 32 + TID]; }
        float m = s * (1.f / 2359296.f);
        float v = q * (1.f / 2359296.f) - m * m;
        float sc = g1[TID] / sqrtf(v + 1e-5f);
        scs[TID] = sc; shs[TID] = be1[TID] - m * sc;
    }
    __syncthreads();
    float scR[8], shR[8];
    {
        int b = TID & 3;
        #pragma unroll
        for (int j = 0; j < 8; j++) { scR[j] = scs[b * 8 + j]; shR[j] = shs[b * 8 + j]; }
    }
    short8 bw[25];
    #pragma unroll
    for (int sh = 0; sh < 25; sh++)
        bw[sh] = *reinterpret_cast<const short8*>(qw2c + ((size_t)sh * 64 + oc0 + lm) * 32 + bq * 8);
    int xy[5];
    #pragma unroll
    for (int kx = 0; kx < 5; kx++) {
        int xx = ox + kx;
        xy[kx] = lr * 784 + xx * 64 + (((bq + (xx >> 1)) & 3) * 16);
    }
    float sacc = 0.f, s2acc = 0.f;
    // ---- prologue: stage sample 0 into buffer 0 ----
    {
        const uint4* src = reinterpret_cast<const uint4*>(y1p + (size_t)n0 * 4608);
        #pragma unroll
        for (int k = 0; k < 3; k++) {
            if (k < 2 || TID < 64) {
                int i = TID + k * 256;
                int pix = i >> 2, b = i & 3;
                int y = pix / 12, xx = pix - y * 12;
                union { uint4 v; u16 u[8]; } in;
                in.v = src[i];
                float f[8];
                #pragma unroll
                for (int j = 0; j < 8; j++)
                    f[j] = fmaxf(fmaf(b2f(in.u[j]), scR[j], shR[j]), 0.f);
                uint4 o = make_uint4(cvt_pk(f[0], f[1]), cvt_pk(f[2], f[3]),
                                     cvt_pk(f[4], f[5]), cvt_pk(f[6], f[7]));
                *reinterpret_cast<uint4*>(hsraw + y * 784 + xx * 64 + (((b + (xx >> 1)) & 3) * 16)) = o;
            }
        }
    }
    #pragma unroll 1
    for (int s = 0; s < 8; s++) {
        __syncthreads();
        // ---- T14 issue-early: next sample's loads into registers (no wait) ----
        uint4 pf0 = {}, pf1 = {}, pf2 = {};
        if (s < 7) {
            const uint4* src = reinterpret_cast<const uint4*>(y1p + (size_t)(n0 + s + 1) * 4608);
            pf0 = src[TID];
            pf1 = src[TID + 256];
            if (TID < 64) pf2 = src[TID + 512];
        }
        // ---- compute from buf[s&1] (LDS-only deps) ----
        const char* hb = hsraw + (s & 1) * 9408;
        f32x4 acc[4] = {{0.f,0.f,0.f,0.f},{0.f,0.f,0.f,0.f},{0.f,0.f,0.f,0.f},{0.f,0.f,0.f,0.f}};
        #pragma unroll
        for (int R = 0; R <= 10; R++) {
            short8 a[5];
            #pragma unroll
            for (int kx = 0; kx < 5; kx++)
                a[kx] = *reinterpret_cast<const short8*>(hb + xy[kx] + R * 784);
            #pragma unroll
            for (int mt = 0; mt < 4; mt++) {
                int ky = R - 2 * mt;
                if (ky < 0 || ky > 4) continue;
                #pragma unroll
                for (int kx = 0; kx < 5; kx++)
                    acc[mt] = __builtin_amdgcn_mfma_f32_16x16x32_bf16(a[kx], bw[ky * 5 + kx], acc[mt], 0, 0, 0);
            }
        }
        int n = n0 + s;
        u16* hp = h2pre + (size_t)n * 1024 + (oc0 + lm) * 16;
        #pragma unroll
        for (int mt = 0; mt < 4; mt++) {
            float v0 = acc[mt][0], v1 = acc[mt][1], v2 = acc[mt][2], v3 = acc[mt][3];
            sacc += v0 + v1 + v2 + v3;
            s2acc += v0 * v0 + v1 * v1 + v2 * v2 + v3 * v3;
            float w0 = fmaxf(v0, v1), w1 = fmaxf(v2, v3);
            float p0 = xmax32(w0);
            float p1 = xmax32(w1);
            if (bq < 2) {
                *reinterpret_cast<unsigned int*>(hp + mt * 4 + bq * 2) = cvt_pk(p0, p1);
            }
        }
        // ---- T14 write-late: vmcnt-wait here, AFTER ~100 MFMAs hid the latency ----
        if (s < 7) {
            char* dst = hsraw + ((s + 1) & 1) * 9408;
            #pragma unroll
            for (int k = 0; k < 3; k++) {
                if (k < 2 || TID < 64) {
                    int i = TID + k * 256;
                    int pix = i >> 2, b = i & 3;
                    int y = pix / 12, xx = pix - y * 12;
                    union { uint4 v; u16 u[8]; } in;
                    in.v = (k == 0) ? pf0 : ((k == 1) ? pf1 : pf2);
                    float f[8];
                    #pragma unroll
                    for (int j = 0; j < 8; j++)
                        f[j] = fmaxf(fmaf(b2f(in.u[j]), scR[j], shR[j]), 0.f);
                    uint4 o = make_uint4(cvt_pk(f[0], f[1]), cvt_pk(f[2], f[3]),
                                         cvt_pk(f[4], f[5]), cvt_pk(f[6], f[7]));
                    *reinterpret_cast<uint4*>(dst + y * 784 + xx * 64 + (((b + (xx >> 1)) & 3) * 16)) = o;
                }
            }
        }
    }
    sacc  += __shfl_xor(sacc, 16);  sacc  += __shfl_xor(sacc, 32);
    s2acc += __shfl_xor(s2acc, 16); s2acc += __shfl_xor(s2acc, 32);
    if (l < 16) { atomicAdd(&sum[oc0 + l], sacc); atomicAdd(&ssq[oc0 + l], s2acc); }
}

// ---------------- fc1: 64x64-tile MFMA GEMM; BN2+relu fused into A-staging ----------------
// r4: cvt_pk staging. r6: T14 pipeline (mirrors conv2's r1 win): double-buffered LDS;
// per K-iteration: [barrier] issue next-K global loads (no wait) -> MFMA on current
// buffer -> cvt+ds_write next buffer. Previously load->cvt->write->barrier->MFMA put
// naked L2 latency on the critical path 16x per block. LDS 18.4->37.4 KB (still >=4
// blocks/CU capacity); VGPR ~120 <= 128 (no occupancy step).
__global__ __launch_bounds__(256) void fc1_k(const u16* __restrict__ h2pre,
                                             const u16* __restrict__ qwf1c,
                                             const float* sum2, const float* ssq2,
                                             const float* g2, const float* be2,
                                             float* __restrict__ y3T,
                                             float* sum3, float* ssq3) {
    __shared__ float4 Asm[2][576], Bsm[2][576];
    __shared__ float sc2s[64], sh2s[64];
    int m0 = blockIdx.x * 64, j0 = blockIdx.y * 64;
    int l = TID & 63, wv = TID >> 6;
    int lm = l & 15, q = l >> 4;
    int r0 = TID >> 3, c0 = TID & 7;
    if (TID < 64) {
        float m = sum2[TID] * (1.f / 262144.f);
        float v = ssq2[TID] * (1.f / 262144.f) - m * m;
        float s = g2[TID] / sqrtf(v + 1e-5f);
        sc2s[TID] = s; sh2s[TID] = be2[TID] - m * s;
    }
    __syncthreads();
    // ---- prologue: stage kc=0 into buffer 0 ----
    {
        u16* AsW = (u16*)Asm[0]; u16* BsW = (u16*)Bsm[0];
        int oc = (c0 * 8) >> 4;
        float sc = sc2s[oc], sh = sh2s[oc];
        #pragma unroll
        for (int i = 0; i < 2; i++) {
            int r = i * 32 + r0;
            union { float4 v; u16 h[8]; } in;
            in.v = *reinterpret_cast<const float4*>(h2pre + (size_t)(m0 + r) * 1024 + c0 * 8);
            float f[8];
            #pragma unroll
            for (int e = 0; e < 8; e++)
                f[e] = fmaxf(fmaf(b2f(in.h[e]), sc, sh), 0.f);
            uint4 o = make_uint4(cvt_pk(f[0], f[1]), cvt_pk(f[2], f[3]),
                                 cvt_pk(f[4], f[5]), cvt_pk(f[6], f[7]));
            *reinterpret_cast<uint4*>(AsW + r * 72 + c0 * 8) = o;
            *reinterpret_cast<float4*>(BsW + r * 72 + c0 * 8) =
                *reinterpret_cast<const float4*>(qwf1c + (size_t)(j0 + r) * 1024 + c0 * 8);
        }
    }
    f32x4 acc[4] = {{0.f,0.f,0.f,0.f},{0.f,0.f,0.f,0.f},{0.f,0.f,0.f,0.f},{0.f,0.f,0.f,0.f}};
    #pragma unroll 1
    for (int kc = 0; kc < 16; kc++) {
        __syncthreads();
        // ---- T14 issue-early: next-K loads into registers (no wait) ----
        float4 pa0, pa1, pb0, pb1;
        if (kc < 15) {
            int kk = (kc + 1) * 64;
            pa0 = *reinterpret_cast<const float4*>(h2pre + (size_t)(m0 + r0) * 1024 + kk + c0 * 8);
            pa1 = *reinterpret_cast<const float4*>(h2pre + (size_t)(m0 + 32 + r0) * 1024 + kk + c0 * 8);
            pb0 = *reinterpret_cast<const float4*>(qwf1c + (size_t)(j0 + r0) * 1024 + kk + c0 * 8);
            pb1 = *reinterpret_cast<const float4*>(qwf1c + (size_t)(j0 + 32 + r0) * 1024 + kk + c0 * 8);
        }
        // ---- MFMA on buf[kc&1] (LDS-only deps) ----
        const u16* AsU = (const u16*)Asm[kc & 1];
        const u16* BsU = (const u16*)Bsm[kc & 1];
        #pragma unroll
        for (int half = 0; half < 2; half++) {
            short8 b = *reinterpret_cast<const short8*>(BsU + (wv * 16 + lm) * 72 + half * 32 + q * 8);
            #pragma unroll
            for (int mt = 0; mt < 4; mt++) {
                short8 a = *reinterpret_cast<const short8*>(AsU + (mt * 16 + lm) * 72 + half * 32 + q * 8);
                acc[mt] = __builtin_amdgcn_mfma_f32_16x16x32_bf16(a, b, acc[mt], 0, 0, 0);
            }
        }
        // ---- T14 write-late: vmcnt-wait here, after the 8 MFMAs hid the latency ----
        if (kc < 15) {
            int kk = (kc + 1) * 64;
            u16* AsW = (u16*)Asm[(kc + 1) & 1];
            u16* BsW = (u16*)Bsm[(kc + 1) & 1];
            int oc = (kk + c0 * 8) >> 4;
            float sc = sc2s[oc], sh = sh2s[oc];
            #pragma unroll
            for (int i = 0; i < 2; i++) {
                int r = i * 32 + r0;
                union { float4 v; u16 h[8]; } in;
                in.v = (i == 0) ? pa0 : pa1;
                float f[8];
                #pragma unroll
                for (int e = 0; e < 8; e++)
                    f[e] = fmaxf(fmaf(b2f(in.h[e]), sc, sh), 0.f);
                uint4 o = make_uint4(cvt_pk(f[0], f[1]), cvt_pk(f[2], f[3]),
                                     cvt_pk(f[4], f[5]), cvt_pk(f[6], f[7]));
                *reinterpret_cast<uint4*>(AsW + r * 72 + c0 * 8) = o;
                *reinterpret_cast<float4*>(BsW + r * 72 + c0 * 8) = (i == 0) ? pb0 : pb1;
            }
        }
    }
    float s = 0.f, s2 = 0.f;
    #pragma unroll
    for (int mt = 0; mt < 4; mt++) {
        *reinterpret_cast<f32x4*>(y3T + (size_t)(j0 + wv * 16 + lm) * 4096 + m0 + mt * 16 + q * 4) = acc[mt];
        #pragma unroll
        for (int i = 0; i < 4; i++) { float v = acc[mt][i]; s += v; s2 = fmaf(v, v, s2); }
    }
    s  += __shfl_xor(s, 16);  s  += __shfl_xor(s, 32);
    s2 += __shfl_xor(s2, 16); s2 += __shfl_xor(s2, 32);
    if (l < 16) {
        atomicAdd(&sum3[j0 + wv * 16 + l], s);
        atomicAdd(&ssq3[j0 + wv * 16 + l], s2);
    }
}

// ---------------- fc2: BN3 inline + relu + GEMV; grid 256 = 16 n x 16 kslices ----------------
__global__ __launch_bounds__(256) void fc2_k(const float* __restrict__ y3T,
                                             const float* sum3, const float* ssq3,
                                             const float* g3, const float* be3,
                                             const float* __restrict__ qwf2,
                                             const float* bf2, float* __restrict__ out) {
    __shared__ float wlds[5120];
    __shared__ float part[15][160];
    __shared__ float sc3s[512], sh3s[512];
    for (int i = TID; i < 5120; i += 256) wlds[i] = qwf2[i];
    for (int k = TID; k < 512; k += 256) {
        float m = sum3[k] * (1.f / 4096.f);
        float v = ssq3[k] * (1.f / 4096.f) - m * m;
        float s = g3[k] / sqrtf(v + 1e-5f);
        sc3s[k] = s; sh3s[k] = be3[k] - m * s;
    }
    __syncthreads();
    int nl = TID & 15, ks = TID >> 4;
    int n = blockIdx.x * 16 + nl;            // grid.x = 256
    float acc[10] = {};
    for (int k = ks * 32; k < ks * 32 + 32; k++) {
        float v = fmaxf(y3T[(size_t)k * 4096 + n] * sc3s[k] + sh3s[k], 0.f);
        #pragma unroll
        for (int o = 0; o < 10; o++) acc[o] = fmaf(v, wlds[o * 512 + k], acc[o]);
    }
    if (ks > 0) {
        #pragma unroll
        for (int o = 0; o < 10; o++) part[ks - 1][o * 16 + nl] = acc[o];
    }
    __syncthreads();
    if (ks == 0) {
        #pragma unroll
        for (int o = 0; o < 10; o++) {
            float r = acc[o] + bf2[o];
            #pragma unroll
            for (int j = 0; j < 15; j++) r += part[j][o * 16 + nl];
            out[n * 10 + o] = r;
        }
    }
}

extern "C" void kernel_launch(void* const* d_in, const int* in_sizes, int n_in,
                              void* d_out, int out_size, void* d_ws, size_t ws_size,
                              hipStream_t stream) {
    char* wsb = (char*)d_ws;
    const float* x   = (const float*)d_in[0];
    const float* w1  = (const float*)d_in[1];
    // b1/b2/bf1 cancel under training-mode BN
    const float* g1  = (const float*)d_in[3];
    const float* be1 = (const float*)d_in[4];
    const float* w2  = (const float*)d_in[5];
    const float* g2  = (const float*)d_in[7];
    const float* be2 = (const float*)d_in[8];
    const float* wf1 = (const float*)d_in[9];
    const float* g3  = (const float*)d_in[11];
    const float* be3 = (const float*)d_in[12];
    const float* wf2 = (const float*)d_in[13];
    const float* bf2 = (const float*)d_in[14];
    float* out = (float*)d_out;

    unsigned int* tmax = (unsigned int*)(wsb + OFF_TMAX);
    float* qw1   = (float*)(wsb + OFF_QW1);
    float* qwf2  = (float*)(wsb + OFF_QWF2);
    u16*   qw2c  = (u16*)(wsb + OFF_QW2C);
    u16*   qwf1c = (u16*)(wsb + OFF_QWF1C);
    u16*   y1p   = (u16*)(wsb + OFF_Y1P);
    u16*   h2pre = (u16*)(wsb + OFF_H2P);
    float* y3    = (float*)(wsb + OFF_Y3);

    float* sum1c = (float*)(wsb + OFF_SUM1C); float* ssq1c = (float*)(wsb + OFF_SSQ1C);
    float* sum2  = (float*)(wsb + OFF_SUM2);  float* ssq2  = (float*)(wsb + OFF_SSQ2);
    float* sum3  = (float*)(wsb + OFF_SUM3);  float* ssq3  = (float*)(wsb + OFF_SSQ3);

    hipMemsetAsync(wsb + STATS_BEG, 0, STATS_END - STATS_BEG, stream);

    absmax_k<<<266, 256, 0, stream>>>(w1, w2, wf1, wf2, tmax);
    quant_all_k<<<2272, 256, 0, stream>>>(w1, w2, wf1, wf2, qw1, qw2c, qwf1c, qwf2, tmax);

    conv1_fused_k<<<1024, 256, 0, stream>>>(x, qw1, y1p, sum1c, ssq1c);
    conv2_k<<<512, 256, 0, stream>>>(y1p, qw2c, h2pre, sum1c, ssq1c, g1, be1, sum2, ssq2);
    fc1_k<<<dim3(64, 8), 256, 0, stream>>>(h2pre, qwf1c, sum2, ssq2, g2, be2, y3, sum3, ssq3);
    fc2_k<<<256, 256, 0, stream>>>(y3, sum3, ssq3, g3, be3, qwf2, bf2, out);
}

// Round 8
// 188.964 us; speedup vs baseline: 1.1759x; 1.0312x over previous
//
#include <hip/hip_runtime.h>

#define TID ((int)threadIdx.x)
typedef unsigned short u16;
typedef short short8 __attribute__((ext_vector_type(8)));
typedef float f32x4 __attribute__((ext_vector_type(4)));

__device__ __forceinline__ u16 f2b(float f) {
    unsigned int x = __float_as_uint(f);
    return (u16)((x + 0x7fffu + ((x >> 16) & 1u)) >> 16);
}
__device__ __forceinline__ float b2f(u16 u) {
    return __uint_as_float(((unsigned int)u) << 16);
}
// RNE f32x2 -> packed bf16x2 in ONE VALU op (bit-identical to f2b pair).
__device__ __forceinline__ unsigned int cvt_pk(float lo, float hi) {
    unsigned int r;
    asm("v_cvt_pk_bf16_f32 %0, %1, %2" : "=v"(r) : "v"(lo), "v"(hi));
    return r;
}

// ---------------- workspace layout (BYTE offsets) ----------------
static constexpr size_t OFF_QW1   = 0;         // 800 f32 [32][25]
static constexpr size_t OFF_QWF2  = 3200;      // 5120 f32 [10][512]
static constexpr size_t OFF_TMAX  = 23680;     // 4 uint
static constexpr size_t OFF_SUM1C = 23808;     // f32 [8 copies][32]
static constexpr size_t OFF_SSQ1C = 24832;     // f32 [8][32]
static constexpr size_t OFF_SUM2  = 25856, OFF_SSQ2 = 26112;   // f32 [64]
static constexpr size_t OFF_SUM3  = 26368, OFF_SSQ3 = 28416;   // f32 [512]
static constexpr size_t STATS_BEG = 23680, STATS_END = 30464;
static constexpr size_t OFF_QW2C  = 30720;     // bf16 [25 shift][64 oc][32 ic]
static constexpr size_t OFF_QWF1C = 133120;    // bf16 [512][1024]
static constexpr size_t OFF_Y1P   = 1181696;   // bf16 [4096][144][32]  PRE-BN pooled conv1
static constexpr size_t OFF_H2P   = 38930432;  // bf16 [4096][1024]     PRE-BN pooled conv2
static constexpr size_t OFF_Y3    = 47319040;  // f32 [512][4096]
// total ~55.7 MB

// ---------------- abs-max of the 4 weight tensors ----------------
__global__ __launch_bounds__(256) void absmax_k(const float* w1, const float* w2,
                                                const float* wf1, const float* wf2,
                                                unsigned int* tmaxbits) {
    int bid = blockIdx.x;
    int b, lb, nb; const float* src; long n;
    if (bid < 1)        { b = 0; src = w1;  n = 800;    lb = bid;       nb = 1;   }
    else if (bid < 9)   { b = 1; src = w2;  n = 51200;  lb = bid - 1;   nb = 8;   }
    else if (bid < 265) { b = 2; src = wf1; n = 524288; lb = bid - 9;   nb = 256; }
    else                { b = 3; src = wf2; n = 5120;   lb = bid - 265; nb = 1;   }
    float m = 0.f;
    for (long i = (long)lb * 256 + TID; i < n; i += (long)nb * 256)
        m = fmaxf(m, fabsf(src[i]));
    __shared__ float red[256];
    red[TID] = m; __syncthreads();
    for (int s = 128; s > 0; s >>= 1) {
        if (TID < s) red[TID] = fmaxf(red[TID], red[TID + s]);
        __syncthreads();
    }
    if (TID == 0) atomicMax(&tmaxbits[b], __float_as_uint(red[0]));
}

// ---------------- all 4 quantizers in one launch ----------------
// r4: quantized bf16 outputs are exact constants {0,±1} -> literal bit patterns.
__global__ __launch_bounds__(256) void quant_all_k(const float* w1, const float* w2,
                                                   const float* wf1, const float* wf2,
                                                   float* qw1, u16* qw2c, u16* qwf1c,
                                                   float* qwf2, const unsigned int* tmax) {
    int bid = blockIdx.x;
    if (bid < 4) {
        int i = bid * 256 + TID; if (i >= 800) return;
        float t = 0.05f * __uint_as_float(tmax[0]);
        float v = w1[i];
        qw1[i] = (v > t) ? 1.f : ((v < -t) ? -1.f : 0.f);
    } else if (bid < 204) {
        int i = (bid - 4) * 256 + TID;       // < 51200
        float t = 0.05f * __uint_as_float(tmax[1]);
        int ic = i & 31, oc = (i >> 5) & 63, sh = i >> 11;
        float v = w2[(oc * 32 + ic) * 25 + sh];
        qw2c[i] = (v > t) ? (u16)0x3F80 : ((v < -t) ? (u16)0xBF80 : (u16)0);
    } else if (bid < 2252) {
        int i = (bid - 204) * 256 + TID;     // < 524288
        float t = 0.05f * __uint_as_float(tmax[2]);
        float v = wf1[i];
        qwf1c[i] = (v > t) ? (u16)0x3F80 : ((v < -t) ? (u16)0xBF80 : (u16)0);
    } else {
        int i = (bid - 2252) * 256 + TID;    // < 5120
        float t = 0.05f * __uint_as_float(tmax[3]);
        float v = wf2[i];
        qwf2[i] = (v > t) ? 1.f : ((v < -t) ? -1.f : 0.f);
    }
}

// ---------------- conv1 via MFMA, samples-as-M ----------------
// Block = 16 samples x (6 pooled rows [ph]) x (6 pooled cols [pch]); grid 1024.
// r4: staging + output conversions via v_cvt_pk_bf16_f32 (RNE, bit-identical).
__global__ __launch_bounds__(256) void conv1_fused_k(const float* __restrict__ x,
                                                     const float* __restrict__ qw1,
                                                     u16* __restrict__ y1p,
                                                     float* sum1c, float* ssq1c) {
    __shared__ __align__(16) u16 xs[16 * 1096];  // [16 smp][rep0 548 | rep1 548]
    int gid = blockIdx.x;                        // 1024 = 256 sg x 2 ph x 2 pch
    int sg = gid >> 2, ph = (gid >> 1) & 1, pch = gid & 1;
    int l = TID & 63, w = TID >> 6;
    int lm = l & 15, q = l >> 4;

    // ---- zero-fill (2192 uint4) ----
    #pragma unroll
    for (int i = 0; i < 9; i++) {
        int idx = TID + i * 256;
        if (idx < 2192) reinterpret_cast<uint4*>(xs)[idx] = make_uint4(0, 0, 0, 0);
    }

    // ---- B fragments (global reads, no LDS dep) ----
    short8 B1[2], B2[2];
    #pragma unroll
    for (int c = 0; c < 2; c++) {
        union { short8 s; u16 h[8]; } b1, b2;
        int ch = c * 16 + lm;
        #pragma unroll
        for (int j = 0; j < 8; j++) {
            float v1 = 0.f, v2 = 0.f;
            if (j < 5) {
                v1 = qw1[ch * 25 + q * 5 + j];
                v2 = qw1[ch * 25 + 20 + j];
            }
            b1.h[j] = f2b(v1);
            b2.h[j] = (q == 0) ? f2b(v2) : (u16)0;
        }
        B1[c] = b1.s; B2[c] = b2.s;
    }
    __syncthreads();

    // ---- stage x rows 12ph..12ph+15 as bf16, 2 shifted replicas ----
    #pragma unroll
    for (int k = 0; k < 7; k++) {
        int i = TID + k * 256;                   // < 1792 exactly
        int smp = i / 112, rem = i % 112;
        int row = rem / 7, c4 = (rem % 7) * 4;
        float4 v = *reinterpret_cast<const float4*>(
            x + (size_t)(sg * 16 + smp) * 784 + (12 * ph + row) * 28 + c4);
        unsigned int r0 = cvt_pk(v.x, v.y), r1 = cvt_pk(v.z, v.w);
        uint2 pk; pk.x = r0; pk.y = r1;
        *reinterpret_cast<uint2*>(xs + smp * 1096 + row * 32 + c4) = pk;
        u16 h[4] = {(u16)r0, (u16)(r0 >> 16), (u16)r1, (u16)(r1 >> 16)};
        u16* b1p = xs + smp * 1096 + 548 + row * 32;
        #pragma unroll
        for (int e = 0; e < 4; e++) {
            int c = c4 + e;
            if (c >= 1) b1p[c - 1] = h[e];
        }
    }
    __syncthreads();

    // ---- compute: wave w handles 9 pooled positions ----
    float s0 = 0.f, s1 = 0.f, q0 = 0.f, q1 = 0.f;
    int laneoff = lm * 1096;
    #pragma unroll 1
    for (int e = 0; e < 9; e++) {
        int pp = w * 9 + e;                      // 0..35
        int prl = pp / 6, pcl = pp - prl * 6;
        f32x4 pm0 = {-3.0e38f, -3.0e38f, -3.0e38f, -3.0e38f};
        f32x4 pm1 = pm0;
        #pragma unroll
        for (int dyx = 0; dyx < 4; dyx++) {
            int dy = dyx >> 1, dx = dyx & 1;
            int oyl = 2 * prl + dy;              // local conv row 0..11
            int ox = 2 * (pch * 6 + pcl) + dx;   // global conv col 0..23
            int r = ox & 1, cb = ox - r;
            const u16* p1 = xs + laneoff + r * 548 + (oyl + q) * 32 + cb;
            const u16* p2 = xs + laneoff + r * 548 + (oyl + 4) * 32 + cb;
            union { short8 s; unsigned int u[4]; } a1, a2;
            #pragma unroll
            for (int t = 0; t < 4; t++) {
                a1.u[t] = *reinterpret_cast<const unsigned int*>(p1 + 2 * t);
                a2.u[t] = *reinterpret_cast<const unsigned int*>(p2 + 2 * t);
            }
            f32x4 d0 = {0.f, 0.f, 0.f, 0.f};
            d0 = __builtin_amdgcn_mfma_f32_16x16x32_bf16(a1.s, B1[0], d0, 0, 0, 0);
            d0 = __builtin_amdgcn_mfma_f32_16x16x32_bf16(a2.s, B2[0], d0, 0, 0, 0);
            f32x4 d1 = {0.f, 0.f, 0.f, 0.f};
            d1 = __builtin_amdgcn_mfma_f32_16x16x32_bf16(a1.s, B1[1], d1, 0, 0, 0);
            d1 = __builtin_amdgcn_mfma_f32_16x16x32_bf16(a2.s, B2[1], d1, 0, 0, 0);
            #pragma unroll
            for (int i = 0; i < 4; i++) {
                float v = d0[i]; s0 += v; q0 = fmaf(v, v, q0);
                float u = d1[i]; s1 += u; q1 = fmaf(u, u, q1);
            }
            pm0 = __builtin_elementwise_max(pm0, d0);
            pm1 = __builtin_elementwise_max(pm1, d1);
        }
        int ppg = (ph * 6 + prl) * 12 + (pch * 6 + pcl);
        #pragma unroll
        for (int i = 0; i < 4; i++) {
            size_t nb = (size_t)(sg * 16 + 4 * q + i) * 4608 + ppg * 32;
            unsigned int r = cvt_pk(pm0[i], pm1[i]);
            y1p[nb + lm]      = (u16)r;
            y1p[nb + 16 + lm] = (u16)(r >> 16);
        }
    }
    // ---- stats: lanes l, l^16, l^32, l^48 share channel (sum over 16 samples) ----
    s0 += __shfl_xor(s0, 16); s0 += __shfl_xor(s0, 32);
    s1 += __shfl_xor(s1, 16); s1 += __shfl_xor(s1, 32);
    q0 += __shfl_xor(q0, 16); q0 += __shfl_xor(q0, 32);
    q1 += __shfl_xor(q1, 16); q1 += __shfl_xor(q1, 32);
    if (l < 16) {
        int slot = (blockIdx.x & 7) * 32;
        atomicAdd(&sum1c[slot + l], s0);
        atomicAdd(&sum1c[slot + 16 + l], s1);
        atomicAdd(&ssq1c[slot + l], q0);
        atomicAdd(&ssq1c[slot + 16 + l], q1);
    }
}

// ---------------- conv2: MFMA implicit conv; BN1+relu in staging; pre-BN pooled epilogue ----------------
// r1: T14 async-STAGE split (44.9->42.0). r4: cvt_pk (42->~40). r5/r6: occupancy levers
// both failed -> limiter is the LDS-read stream (1760 ds_read_b128/block @ ~12cy).
// r7: 2-SAMPLE M-PACKING. MFMA M=16 rows now = 8 cols x 2 SAMPLES (fragment-row bit3
// = sample), not 8 cols x 2 conv-rows of one sample. Each A-read at input row R serves
// BOTH samples and up to 5 of 8 per-row accumulators: 200 MFMA / 60 reads = 3.3/read
// (was 100/55 = 1.8). Per block: LDS reads 1760 -> 960 (-45%), barriers 8 -> 4, MFMA
// unchanged, bw[25] unchanged. acc 16->32 VGPR, prefetch 12->20 (total ~220, harmless:
// grid-limited 2 blocks/CU; launch_bounds(256,2) holds the 2-wave/SIMD floor).
// Pooling row-pairs become IN-REGISTER (acc[2t] vs acc[2t+1]) -> xmax32 eliminated.
// D-row map (m89 layout): r=4bq+i -> sample=bq>>1, col=4(bq&1)+i; pooled store layout
// pr*4+pc preserved bit-for-bit for fc1.
__global__ __launch_bounds__(256, 2) void conv2_k(const u16* __restrict__ y1p,
                                                  const u16* __restrict__ qw2c,
                                                  u16* __restrict__ h2pre,
                                                  const float* sum1c, const float* ssq1c,
                                                  const float* g1, const float* be1,
                                                  float* sum, float* ssq) {
    __shared__ float4 hsm4[2352];            // 2 buffers x 18816 B (2 samples each)
    __shared__ float scs[32], shs[32];
    char* hsraw = (char*)hsm4;
    int n0 = blockIdx.x * 8;                 // grid.x = 512
    int l = TID & 63, wv = TID >> 6;
    int oc0 = wv * 16;
    int lm = l & 15, sp = (l >> 3) & 1, ox = l & 7, bq = l >> 4;
    if (TID < 32) {
        float s = 0.f, q = 0.f;
        #pragma unroll
        for (int r = 0; r < 8; r++) { s += sum1c[r * 32 + TID]; q += ssq1c[r * 32 + TID]; }
        float m = s * (1.f / 2359296.f);
        float v = q * (1.f / 2359296.f) - m * m;
        float sc = g1[TID] / sqrtf(v + 1e-5f);
        scs[TID] = sc; shs[TID] = be1[TID] - m * sc;
    }
    __syncthreads();
    float scR[8], shR[8];
    {
        int b = TID & 3;
        #pragma unroll
        for (int j = 0; j < 8; j++) { scR[j] = scs[b * 8 + j]; shR[j] = shs[b * 8 + j]; }
    }
    short8 bw[25];
    #pragma unroll
    for (int sh = 0; sh < 25; sh++)
        bw[sh] = *reinterpret_cast<const short8*>(qw2c + ((size_t)sh * 64 + oc0 + lm) * 32 + bq * 8);
    // A-read base: fragment row bit3 = sample -> sp*9408; col = ox.
    int xy[5];
    #pragma unroll
    for (int kx = 0; kx < 5; kx++) {
        int xx = ox + kx;
        xy[kx] = sp * 9408 + xx * 64 + (((bq + (xx >> 1)) & 3) * 16);
    }
    float sacc = 0.f, s2acc = 0.f;
    // ---- prologue: stage sample pair (n0, n0+1) into buffer 0 ----
    {
        const uint4* src = reinterpret_cast<const uint4*>(y1p + (size_t)n0 * 4608);
        #pragma unroll
        for (int k = 0; k < 5; k++) {
            if (k < 4 || TID < 128) {
                int i = TID + k * 256;           // < 1152 (2 samples x 576)
                int smp = (i >= 576) ? 1 : 0;
                int j = i - smp * 576;
                int pix = j >> 2, b = j & 3;
                int y = pix / 12, xx = pix - y * 12;
                union { uint4 v; u16 u[8]; } in;
                in.v = src[i];
                float f[8];
                #pragma unroll
                for (int e = 0; e < 8; e++)
                    f[e] = fmaxf(fmaf(b2f(in.u[e]), scR[e], shR[e]), 0.f);
                uint4 o = make_uint4(cvt_pk(f[0], f[1]), cvt_pk(f[2], f[3]),
                                     cvt_pk(f[4], f[5]), cvt_pk(f[6], f[7]));
                *reinterpret_cast<uint4*>(hsraw + smp * 9408 + y * 784 + xx * 64 +
                                          (((b + (xx >> 1)) & 3) * 16)) = o;
            }
        }
    }
    #pragma unroll 1
    for (int t = 0; t < 4; t++) {
        __syncthreads();
        // ---- T14 issue-early: next sample-pair loads into registers (no wait) ----
        uint4 pf[5] = {};
        if (t < 3) {
            const uint4* src = reinterpret_cast<const uint4*>(y1p + (size_t)(n0 + 2 * (t + 1)) * 4608);
            #pragma unroll
            for (int k = 0; k < 5; k++)
                if (k < 4 || TID < 128) pf[k] = src[TID + k * 256];
        }
        // ---- compute from buf[t&1] (LDS-only deps) ----
        const char* hb = hsraw + (t & 1) * 18816;
        f32x4 acc[8] = {{0.f,0.f,0.f,0.f},{0.f,0.f,0.f,0.f},{0.f,0.f,0.f,0.f},{0.f,0.f,0.f,0.f},
                        {0.f,0.f,0.f,0.f},{0.f,0.f,0.f,0.f},{0.f,0.f,0.f,0.f},{0.f,0.f,0.f,0.f}};
        #pragma unroll
        for (int R = 0; R <= 11; R++) {
            short8 a[5];
            #pragma unroll
            for (int kx = 0; kx < 5; kx++)
                a[kx] = *reinterpret_cast<const short8*>(hb + xy[kx] + R * 784);
            #pragma unroll
            for (int mt = 0; mt < 8; mt++) {
                int ky = R - mt;                 // output row mt needs input row mt+ky
                if (ky < 0 || ky > 4) continue;
                #pragma unroll
                for (int kx = 0; kx < 5; kx++)
                    acc[mt] = __builtin_amdgcn_mfma_f32_16x16x32_bf16(a[kx], bw[ky * 5 + kx], acc[mt], 0, 0, 0);
            }
        }
        // ---- epilogue: lane's sample = bq>>1; pooled cols (bq&1)*2 + {0,1}; rows in-reg ----
        int n = n0 + 2 * t + (bq >> 1);
        u16* hp = h2pre + (size_t)n * 1024 + (oc0 + lm) * 16 + (bq & 1) * 2;
        #pragma unroll
        for (int tp = 0; tp < 4; tp++) {
            f32x4 A0 = acc[2 * tp], A1 = acc[2 * tp + 1];
            float v0 = A0[0], v1 = A0[1], v2 = A0[2], v3 = A0[3];
            float u0 = A1[0], u1 = A1[1], u2 = A1[2], u3 = A1[3];
            sacc  += v0 + v1 + v2 + v3 + u0 + u1 + u2 + u3;
            s2acc += v0*v0 + v1*v1 + v2*v2 + v3*v3 + u0*u0 + u1*u1 + u2*u2 + u3*u3;
            float p0 = fmaxf(fmaxf(v0, v1), fmaxf(u0, u1));
            float p1 = fmaxf(fmaxf(v2, v3), fmaxf(u2, u3));
            *reinterpret_cast<unsigned int*>(hp + tp * 4) = cvt_pk(p0, p1);
        }
        // ---- T14 write-late: vmcnt-wait here, AFTER 200 MFMAs hid the latency ----
        if (t < 3) {
            char* dst = hsraw + ((t + 1) & 1) * 18816;
            #pragma unroll
            for (int k = 0; k < 5; k++) {
                if (k < 4 || TID < 128) {
                    int i = TID + k * 256;
                    int smp = (i >= 576) ? 1 : 0;
                    int j = i - smp * 576;
                    int pix = j >> 2, b = j & 3;
                    int y = pix / 12, xx = pix - y * 12;
                    union { uint4 v; u16 u[8]; } in;
                    in.v = pf[k];
                    float f[8];
                    #pragma unroll
                    for (int e = 0; e < 8; e++)
                        f[e] = fmaxf(fmaf(b2f(in.u[e]), scR[e], shR[e]), 0.f);
                    uint4 o = make_uint4(cvt_pk(f[0], f[1]), cvt_pk(f[2], f[3]),
                                         cvt_pk(f[4], f[5]), cvt_pk(f[6], f[7]));
                    *reinterpret_cast<uint4*>(dst + smp * 9408 + y * 784 + xx * 64 +
                                              (((b + (xx >> 1)) & 3) * 16)) = o;
                }
            }
        }
    }
    sacc  += __shfl_xor(sacc, 16);  sacc  += __shfl_xor(sacc, 32);
    s2acc += __shfl_xor(s2acc, 16); s2acc += __shfl_xor(s2acc, 32);
    if (l < 16) { atomicAdd(&sum[oc0 + l], sacc); atomicAdd(&ssq[oc0 + l], s2acc); }
}

// ---------------- fc1: 64x64-tile MFMA GEMM; BN2+relu fused into A-staging ----------------
// r4: cvt_pk staging. r6: T14 pipeline (measured win, part of 208->195): double-buffered
// LDS; per K-iteration: [barrier] issue next-K loads (no wait) -> MFMA current buffer ->
// cvt+ds_write next buffer.
__global__ __launch_bounds__(256) void fc1_k(const u16* __restrict__ h2pre,
                                             const u16* __restrict__ qwf1c,
                                             const float* sum2, const float* ssq2,
                                             const float* g2, const float* be2,
                                             float* __restrict__ y3T,
                                             float* sum3, float* ssq3) {
    __shared__ float4 Asm[2][576], Bsm[2][576];
    __shared__ float sc2s[64], sh2s[64];
    int m0 = blockIdx.x * 64, j0 = blockIdx.y * 64;
    int l = TID & 63, wv = TID >> 6;
    int lm = l & 15, q = l >> 4;
    int r0 = TID >> 3, c0 = TID & 7;
    if (TID < 64) {
        float m = sum2[TID] * (1.f / 262144.f);
        float v = ssq2[TID] * (1.f / 262144.f) - m * m;
        float s = g2[TID] / sqrtf(v + 1e-5f);
        sc2s[TID] = s; sh2s[TID] = be2[TID] - m * s;
    }
    __syncthreads();
    // ---- prologue: stage kc=0 into buffer 0 ----
    {
        u16* AsW = (u16*)Asm[0]; u16* BsW = (u16*)Bsm[0];
        int oc = (c0 * 8) >> 4;
        float sc = sc2s[oc], sh = sh2s[oc];
        #pragma unroll
        for (int i = 0; i < 2; i++) {
            int r = i * 32 + r0;
            union { float4 v; u16 h[8]; } in;
            in.v = *reinterpret_cast<const float4*>(h2pre + (size_t)(m0 + r) * 1024 + c0 * 8);
            float f[8];
            #pragma unroll
            for (int e = 0; e < 8; e++)
                f[e] = fmaxf(fmaf(b2f(in.h[e]), sc, sh), 0.f);
            uint4 o = make_uint4(cvt_pk(f[0], f[1]), cvt_pk(f[2], f[3]),
                                 cvt_pk(f[4], f[5]), cvt_pk(f[6], f[7]));
            *reinterpret_cast<uint4*>(AsW + r * 72 + c0 * 8) = o;
            *reinterpret_cast<float4*>(BsW + r * 72 + c0 * 8) =
                *reinterpret_cast<const float4*>(qwf1c + (size_t)(j0 + r) * 1024 + c0 * 8);
        }
    }
    f32x4 acc[4] = {{0.f,0.f,0.f,0.f},{0.f,0.f,0.f,0.f},{0.f,0.f,0.f,0.f},{0.f,0.f,0.f,0.f}};
    #pragma unroll 1
    for (int kc = 0; kc < 16; kc++) {
        __syncthreads();
        // ---- T14 issue-early: next-K loads into registers (no wait) ----
        float4 pa0, pa1, pb0, pb1;
        if (kc < 15) {
            int kk = (kc + 1) * 64;
            pa0 = *reinterpret_cast<const float4*>(h2pre + (size_t)(m0 + r0) * 1024 + kk + c0 * 8);
            pa1 = *reinterpret_cast<const float4*>(h2pre + (size_t)(m0 + 32 + r0) * 1024 + kk + c0 * 8);
            pb0 = *reinterpret_cast<const float4*>(qwf1c + (size_t)(j0 + r0) * 1024 + kk + c0 * 8);
            pb1 = *reinterpret_cast<const float4*>(qwf1c + (size_t)(j0 + 32 + r0) * 1024 + kk + c0 * 8);
        }
        // ---- MFMA on buf[kc&1] (LDS-only deps) ----
        const u16* AsU = (const u16*)Asm[kc & 1];
        const u16* BsU = (const u16*)Bsm[kc & 1];
        #pragma unroll
        for (int half = 0; half < 2; half++) {
            short8 b = *reinterpret_cast<const short8*>(BsU + (wv * 16 + lm) * 72 + half * 32 + q * 8);
            #pragma unroll
            for (int mt = 0; mt < 4; mt++) {
                short8 a = *reinterpret_cast<const short8*>(AsU + (mt * 16 + lm) * 72 + half * 32 + q * 8);
                acc[mt] = __builtin_amdgcn_mfma_f32_16x16x32_bf16(a, b, acc[mt], 0, 0, 0);
            }
        }
        // ---- T14 write-late: vmcnt-wait here, after the 8 MFMAs hid the latency ----
        if (kc < 15) {
            int kk = (kc + 1) * 64;
            u16* AsW = (u16*)Asm[(kc + 1) & 1];
            u16* BsW = (u16*)Bsm[(kc + 1) & 1];
            int oc = (kk + c0 * 8) >> 4;
            float sc = sc2s[oc], sh = sh2s[oc];
            #pragma unroll
            for (int i = 0; i < 2; i++) {
                int r = i * 32 + r0;
                union { float4 v; u16 h[8]; } in;
                in.v = (i == 0) ? pa0 : pa1;
                float f[8];
                #pragma unroll
                for (int e = 0; e < 8; e++)
                    f[e] = fmaxf(fmaf(b2f(in.h[e]), sc, sh), 0.f);
                uint4 o = make_uint4(cvt_pk(f[0], f[1]), cvt_pk(f[2], f[3]),
                                     cvt_pk(f[4], f[5]), cvt_pk(f[6], f[7]));
                *reinterpret_cast<uint4*>(AsW + r * 72 + c0 * 8) = o;
                *reinterpret_cast<float4*>(BsW + r * 72 + c0 * 8) = (i == 0) ? pb0 : pb1;
            }
        }
    }
    float s = 0.f, s2 = 0.f;
    #pragma unroll
    for (int mt = 0; mt < 4; mt++) {
        *reinterpret_cast<f32x4*>(y3T + (size_t)(j0 + wv * 16 + lm) * 4096 + m0 + mt * 16 + q * 4) = acc[mt];
        #pragma unroll
        for (int i = 0; i < 4; i++) { float v = acc[mt][i]; s += v; s2 = fmaf(v, v, s2); }
    }
    s  += __shfl_xor(s, 16);  s  += __shfl_xor(s, 32);
    s2 += __shfl_xor(s2, 16); s2 += __shfl_xor(s2, 32);
    if (l < 16) {
        atomicAdd(&sum3[j0 + wv * 16 + l], s);
        atomicAdd(&ssq3[j0 + wv * 16 + l], s2);
    }
}

// ---------------- fc2: BN3 inline + relu + GEMV; grid 256 = 16 n x 16 kslices ----------------
__global__ __launch_bounds__(256) void fc2_k(const float* __restrict__ y3T,
                                             const float* sum3, const float* ssq3,
                                             const float* g3, const float* be3,
                                             const float* __restrict__ qwf2,
                                             const float* bf2, float* __restrict__ out) {
    __shared__ float wlds[5120];
    __shared__ float part[15][160];
    __shared__ float sc3s[512], sh3s[512];
    for (int i = TID; i < 5120; i += 256) wlds[i] = qwf2[i];
    for (int k = TID; k < 512; k += 256) {
        float m = sum3[k] * (1.f / 4096.f);
        float v = ssq3[k] * (1.f / 4096.f) - m * m;
        float s = g3[k] / sqrtf(v + 1e-5f);
        sc3s[k] = s; sh3s[k] = be3[k] - m * s;
    }
    __syncthreads();
    int nl = TID & 15, ks = TID >> 4;
    int n = blockIdx.x * 16 + nl;            // grid.x = 256
    float acc[10] = {};
    for (int k = ks * 32; k < ks * 32 + 32; k++) {
        float v = fmaxf(y3T[(size_t)k * 4096 + n] * sc3s[k] + sh3s[k], 0.f);
        #pragma unroll
        for (int o = 0; o < 10; o++) acc[o] = fmaf(v, wlds[o * 512 + k], acc[o]);
    }
    if (ks > 0) {
        #pragma unroll
        for (int o = 0; o < 10; o++) part[ks - 1][o * 16 + nl] = acc[o];
    }
    __syncthreads();
    if (ks == 0) {
        #pragma unroll
        for (int o = 0; o < 10; o++) {
            float r = acc[o] + bf2[o];
            #pragma unroll
            for (int j = 0; j < 15; j++) r += part[j][o * 16 + nl];
            out[n * 10 + o] = r;
        }
    }
}

extern "C" void kernel_launch(void* const* d_in, const int* in_sizes, int n_in,
                              void* d_out, int out_size, void* d_ws, size_t ws_size,
                              hipStream_t stream) {
    char* wsb = (char*)d_ws;
    const float* x   = (const float*)d_in[0];
    const float* w1  = (const float*)d_in[1];
    // b1/b2/bf1 cancel under training-mode BN
    const float* g1  = (const float*)d_in[3];
    const float* be1 = (const float*)d_in[4];
    const float* w2  = (const float*)d_in[5];
    const float* g2  = (const float*)d_in[7];
    const float* be2 = (const float*)d_in[8];
    const float* wf1 = (const float*)d_in[9];
    const float* g3  = (const float*)d_in[11];
    const float* be3 = (const float*)d_in[12];
    const float* wf2 = (const float*)d_in[13];
    const float* bf2 = (const float*)d_in[14];
    float* out = (float*)d_out;

    unsigned int* tmax = (unsigned int*)(wsb + OFF_TMAX);
    float* qw1   = (float*)(wsb + OFF_QW1);
    float* qwf2  = (float*)(wsb + OFF_QWF2);
    u16*   qw2c  = (u16*)(wsb + OFF_QW2C);
    u16*   qwf1c = (u16*)(wsb + OFF_QWF1C);
    u16*   y1p   = (u16*)(wsb + OFF_Y1P);
    u16*   h2pre = (u16*)(wsb + OFF_H2P);
    float* y3    = (float*)(wsb + OFF_Y3);

    float* sum1c = (float*)(wsb + OFF_SUM1C); float* ssq1c = (float*)(wsb + OFF_SSQ1C);
    float* sum2  = (float*)(wsb + OFF_SUM2);  float* ssq2  = (float*)(wsb + OFF_SSQ2);
    float* sum3  = (float*)(wsb + OFF_SUM3);  float* ssq3  = (float*)(wsb + OFF_SSQ3);

    hipMemsetAsync(wsb + STATS_BEG, 0, STATS_END - STATS_BEG, stream);

    absmax_k<<<266, 256, 0, stream>>>(w1, w2, wf1, wf2, tmax);
    quant_all_k<<<2272, 256, 0, stream>>>(w1, w2, wf1, wf2, qw1, qw2c, qwf1c, qwf2, tmax);

    conv1_fused_k<<<1024, 256, 0, stream>>>(x, qw1, y1p, sum1c, ssq1c);
    conv2_k<<<512, 256, 0, stream>>>(y1p, qw2c, h2pre, sum1c, ssq1c, g1, be1, sum2, ssq2);
    fc1_k<<<dim3(64, 8), 256, 0, stream>>>(h2pre, qwf1c, sum2, ssq2, g2, be2, y3, sum3, ssq3);
    fc2_k<<<256, 256, 0, stream>>>(y3, sum3, ssq3, g3, be3, qwf2, bf2, out);
}